// Round 1
// baseline (151.188 us; speedup 1.0000x reference)
//
#include <hip/hip_runtime.h>
#include <hip/hip_bf16.h>
#include <type_traits>

#define NN   8000
#define NE   64000
#define NE2  72000   // edges + self loops
#define NH   8
#define OC   512
#define HC   4096    // NH*OC
#define KIN  128
#define NOUT 512
#define YW   1024    // NH*KIN
#define MAXDEG 64    // in-degree = 1 + Binomial(64000,1/8000); P(>63) astronomically small
#define NEG_SLOPE 0.2f

using bf16 = __hip_bfloat16;
typedef float  f32x4  __attribute__((ext_vector_type(4)));
typedef __bf16 bf16x8 __attribute__((ext_vector_type(8)));

static __device__ __forceinline__ void gld_lds16(const bf16* g, bf16* l){
    __builtin_amdgcn_global_load_lds(
        (const __attribute__((address_space(1))) unsigned int*)g,
        (__attribute__((address_space(3))) unsigned int*)l, 16, 0, 0);
}

struct Acc24 { f32x4 a[2][4]; };

// 64x128 MFMA tile, LDS double-buffered, both operands bf16 k-contiguous.
static __device__ __forceinline__ void gemm64x128(
    const bf16* __restrict__ A, int lda, const bf16* __restrict__ BT, int ldb,
    int K, bf16* sA, bf16* sB, int tid, Acc24& acc)
{
    const int lane = tid & 63;
    const int w    = tid >> 6;
    const int wm   = w >> 1, wn = w & 1;
    const int m16  = lane & 15, q = lane >> 4;
    const int rA = tid >> 2,  kA = (tid & 3) * 8;
    const int cB0 = tid, cB1 = 256 + tid;
    const int rB0 = cB0 >> 2, kB0 = (cB0 & 3) * 8;
    const int rB1 = cB1 >> 2, kB1 = (cB1 & 3) * 8;
    const size_t gA  = (size_t)rA  * lda + kA;
    const size_t gB0 = (size_t)rB0 * ldb + kB0;
    const size_t gB1 = (size_t)rB1 * ldb + kB1;

    #pragma unroll
    for (int i=0;i<2;++i)
        #pragma unroll
        for (int j=0;j<4;++j)
            #pragma unroll
            for (int r=0;r<4;++r) acc.a[i][j][r] = 0.f;

    gld_lds16(A  + gA,  sA + tid*8);
    gld_lds16(BT + gB0, sB + cB0*8);
    gld_lds16(BT + gB1, sB + cB1*8);
    __syncthreads();

    const int nIter = K / 32;
    for (int it = 0; it < nIter; ++it){
        const int cur = it & 1, nxt = cur ^ 1;
        bf16x8 af[2], bfr[4];
        #pragma unroll
        for (int i=0;i<2;++i)
            af[i]  = *(const bf16x8*)(const void*)(sA + cur*64*32 + ((wm*32 + i*16 + m16)*32 + q*8));
        #pragma unroll
        for (int j=0;j<4;++j)
            bfr[j] = *(const bf16x8*)(const void*)(sB + cur*128*32 + ((wn*64 + j*16 + m16)*32 + q*8));
        if (it + 1 < nIter){
            int ko = (it+1) * 32;
            gld_lds16(A  + gA  + ko, sA + nxt*64*32 + tid*8);
            gld_lds16(BT + gB0 + ko, sB + nxt*128*32 + cB0*8);
            gld_lds16(BT + gB1 + ko, sB + nxt*128*32 + cB1*8);
        }
        #pragma unroll
        for (int i=0;i<2;++i)
            #pragma unroll
            for (int j=0;j<4;++j)
                acc.a[i][j] = __builtin_amdgcn_mfma_f32_16x16x32_bf16(af[i], bfr[j], acc.a[i][j], 0, 0, 0);
        __syncthreads();
    }
}

// ================= phase A: all independent preprocessing =================
// [0,128):   W_gat->bf16 (Wg rows 0..127) + v[k][o]
// [128,160): b_eff[o] = sum_c b_gat[c]*W_lin[c][o]  (fp32, atomicAdd partials)
// [160,442): edge bucket fill: esrc[dst*64 + pos], pos = atomicAdd(cursor)
#define VSRC_NB   128
#define BEFF_BASE 128
#define CNT_BASE  160
#define PHA_NB    442

__global__ __launch_bounds__(256) void k_phaseA(
    const float* __restrict__ b_gat, const float* __restrict__ W_gat,
    const float* __restrict__ att_src, const float* __restrict__ att_dst,
    const float* __restrict__ W_lin,
    const int* __restrict__ eidx,
    bf16* __restrict__ Wg, float* __restrict__ v,
    float* __restrict__ b_eff,
    int* __restrict__ cursors, int* __restrict__ esrc)
{
    const int bid = blockIdx.x;
    const int tid = threadIdx.x;

    if (bid < VSRC_NB){
        int k = bid;
        int lane = tid & 63, g = tid >> 6;
        for (int hh = g; hh < NH; hh += 4){
            const float* wp = W_gat + (size_t)k*HC + hh*OC;
            bf16*        wb = Wg    + (size_t)k*HC + hh*OC;
            const float* as = att_src + hh*OC;
            const float* ad = att_dst + hh*OC;
            float ss = 0.f, sd = 0.f;
            #pragma unroll
            for (int c0=0; c0<OC; c0+=64){
                float wv = wp[c0+lane];
                wb[c0+lane] = __float2bfloat16(wv);
                ss = fmaf(wv, as[c0+lane], ss);
                sd = fmaf(wv, ad[c0+lane], sd);
            }
            #pragma unroll
            for (int off=32; off; off>>=1){
                ss += __shfl_down(ss, off);
                sd += __shfl_down(sd, off);
            }
            if (lane == 0){
                v[k*16 + hh]     = ss;
                v[k*16 + 8 + hh] = sd;
            }
        }
    } else if (bid < CNT_BASE){
        // b_eff partials: block covers c in [b*128, b*128+128)
        int b = bid - BEFF_BASE;
        int o = tid * 2;
        const float* bg = b_gat + b*128;
        const float* wl = W_lin + (size_t)b*128*NOUT + o;
        float a0 = 0.f, a1 = 0.f;
        #pragma unroll 4
        for (int c=0; c<128; ++c){
            float bv = bg[c];
            float2 wv = *(const float2*)(wl + (size_t)c*NOUT);
            a0 = fmaf(bv, wv.x, a0);
            a1 = fmaf(bv, wv.y, a1);
        }
        atomicAdd(b_eff + o,     a0);
        atomicAdd(b_eff + o + 1, a1);
    } else {
        int e = (bid - CNT_BASE)*256 + tid;
        if (e < NE2){
            int src, dst;
            if (e < NE){ src = eidx[e]; dst = eidx[NE+e]; } else { src = dst = e - NE; }
            int pos = atomicAdd(&cursors[dst], 1);
            if (pos < MAXDEG) esrc[dst*MAXDEG + pos] = src;
        }
    }
}

// ================= phase B: Wc GEMM (64 blocks) + attn2 (500 blocks) =========
// GEMM: D[k'][o] = sum_c Wg[k'][h*512+c] * W_lin[h*512+c][o], k' in [0,128)
//       -> WcT[o][h*128+k']   (in-kernel W_lin transpose+cvt through LDS)
// attn2: a_src/a_dst[n][h] = x[n] . v[:,h]
#define PB_GEMM_NB 64
#define ATT_BASE   64
#define PHB_NB     564

__global__ __launch_bounds__(256) void k_phaseB(
    const bf16* __restrict__ Wg, const float* __restrict__ W_lin,
    bf16* __restrict__ WcT,
    const float* __restrict__ x, const float* __restrict__ v,
    float* __restrict__ a_src, float* __restrict__ a_dst)
{
    __shared__ __align__(16) char smem_raw[16*132*2*4];   // 16.9 KB, unioned
    const int bid = blockIdx.x;
    const int tid = threadIdx.x;

    if (bid < PB_GEMM_NB){
        bf16* sA = (bf16*)smem_raw;              // 64*32*2B  = 4 KB
        bf16* sB = (bf16*)smem_raw + 64*32;      // 128*32*2B = 8 KB

        const int head = bid >> 3;
        const int rem  = bid & 7;
        const int m0   = (rem >> 2) * 64;      // k'-tile: 0,64
        const int n0   = (rem & 3) * 128;      // o-tile
        const int lane = tid & 63;
        const int w = tid >> 6, wm = w >> 1, wn = w & 1;
        const int m16 = lane & 15, q = lane >> 4;

        const int rA = tid >> 2, kA = (tid & 3) * 8;
        const bf16* Abase = Wg + (size_t)(m0 + rA)*HC + head*OC + kA;

        f32x4 acc[2][4];
        #pragma unroll
        for (int i=0;i<2;++i)
            #pragma unroll
            for (int j=0;j<4;++j)
                #pragma unroll
                for (int r=0;r<4;++r) acc[i][j][r] = 0.f;

        for (int kc = 0; kc < OC; kc += 32){
            __syncthreads();   // prev iter's LDS reads complete
            gld_lds16(Abase + kc, sA + tid*8);
            #pragma unroll
            for (int u=0; u<4; ++u){
                int idx = tid*4 + u;              // 0..1023
                int r    = idx >> 5;              // c_local 0..31
                int gcol = (idx & 31) * 4;        // o_local group
                const float* src = W_lin + (size_t)(head*OC + kc + r)*NOUT + n0 + gcol;
                float4 vv = *(const float4*)src;
                sB[(gcol+0)*32 + r] = __float2bfloat16(vv.x);
                sB[(gcol+1)*32 + r] = __float2bfloat16(vv.y);
                sB[(gcol+2)*32 + r] = __float2bfloat16(vv.z);
                sB[(gcol+3)*32 + r] = __float2bfloat16(vv.w);
            }
            __syncthreads();   // staging complete (incl. vmcnt drain for gld_lds)
            bf16x8 af[2], bfr[4];
            #pragma unroll
            for (int i=0;i<2;++i)
                af[i]  = *(const bf16x8*)(const void*)(sA + ((wm*32 + i*16 + m16)*32 + q*8));
            #pragma unroll
            for (int j=0;j<4;++j)
                bfr[j] = *(const bf16x8*)(const void*)(sB + ((wn*64 + j*16 + m16)*32 + q*8));
            #pragma unroll
            for (int i=0;i<2;++i)
                #pragma unroll
                for (int j=0;j<4;++j)
                    acc[i][j] = __builtin_amdgcn_mfma_f32_16x16x32_bf16(af[i], bfr[j], acc[i][j], 0, 0, 0);
        }

        // writeout: rows all < 128 now (bias handled in phaseA)
        #pragma unroll
        for (int i=0;i<2;++i){
            int row_base = m0 + wm*32 + i*16 + q*4;
            #pragma unroll
            for (int j=0;j<4;++j){
                int col = n0 + wn*64 + j*16 + m16;
                ushort4 pk;
                bf16 b0 = __float2bfloat16(acc[i][j][0]);
                bf16 b1 = __float2bfloat16(acc[i][j][1]);
                bf16 b2 = __float2bfloat16(acc[i][j][2]);
                bf16 b3 = __float2bfloat16(acc[i][j][3]);
                pk.x = *(unsigned short*)&b0; pk.y = *(unsigned short*)&b1;
                pk.z = *(unsigned short*)&b2; pk.w = *(unsigned short*)&b3;
                *reinterpret_cast<ushort4*>(WcT + (size_t)col*YW + head*KIN + row_base) = pk;
            }
        }
        return;
    }

    // ---- attn2 ----
    float (*xs)[132] = (float(*)[132])smem_raw;
    float (*vt)[132] = (float(*)[132])(smem_raw + 16*132*4);
    int node0 = (bid - ATT_BASE) * 16;
    {
        const float* xg = x + (size_t)node0*KIN;
        int row = tid >> 4, co = (tid & 15) * 8;
        float4 v0 = *(const float4*)(xg + row*KIN + co);
        float4 v1 = *(const float4*)(xg + row*KIN + co + 4);
        *(float4*)&xs[row][co]     = v0;
        *(float4*)&xs[row][co + 4] = v1;
    }
    {
        int base = tid*8;
        #pragma unroll
        for (int j=0;j<8;++j){
            int idx = base + j;
            vt[idx & 15][idx >> 4] = v[idx];
        }
    }
    __syncthreads();
    int ln = tid >> 4, o = tid & 15;
    float acc = 0.f;
    #pragma unroll
    for (int k0=0;k0<KIN;k0+=4){
        float4 xv = *(const float4*)&xs[ln][k0];
        float4 vv = *(const float4*)&vt[o][k0];
        acc += xv.x*vv.x + xv.y*vv.y + xv.z*vv.z + xv.w*vv.w;
    }
    int node = node0 + ln;
    if (o < 8) a_src[node*NH + o]     = acc;
    else       a_dst[node*NH + o - 8] = acc;
}

// ================= Y aggregation (bucketed esrc) =========
__global__ __launch_bounds__(256) void k_agg(const int* __restrict__ cnts,
    const int* __restrict__ esrc, const float* __restrict__ a_src,
    const float* __restrict__ a_dst, const float* __restrict__ x,
    bf16* __restrict__ Y)
{
    int node = blockIdx.x*4 + (threadIdx.x >> 6);
    int lane = threadIdx.x & 63;
    int s0 = node*MAXDEG, s1 = s0 + cnts[node];
    int g = lane >> 3, h = lane & 7;
    float adl = a_dst[node*NH + h];
    float m = -1e30f, sum = 0.f;
    for (int e = s0 + g; e < s1; e += 8){
        float l = a_src[esrc[e]*NH + h] + adl;
        l = l > 0.f ? l : NEG_SLOPE*l;
        float mn = fmaxf(m, l);
        sum = sum*__expf(m - mn) + __expf(l - mn);
        m = mn;
    }
    #pragma unroll
    for (int d=8; d<64; d<<=1){
        float mo = __shfl_xor(m, d);
        float so = __shfl_xor(sum, d);
        float mn = fmaxf(m, mo);
        sum = sum*__expf(m - mn) + so*__expf(mo - mn);
        m = mn;
    }
    float inv = 1.f / (sum + 1e-16f);
    float acc[16];
    #pragma unroll
    for (int j=0;j<16;++j) acc[j] = 0.f;
    for (int s=s0; s<s1; ++s){
        int src = esrc[s];
        float wl = 0.f;
        if (lane < 8){
            float l = a_src[src*NH + lane] + adl;
            l = l > 0.f ? l : NEG_SLOPE*l;
            wl = __expf(l - m) * inv;
        }
        float2 xv = *(const float2*)(x + (size_t)src*KIN + lane*2);
        #pragma unroll
        for (int hh=0; hh<8; ++hh){
            float wh = __shfl(wl, hh);
            acc[hh*2]   = fmaf(wh, xv.x, acc[hh*2]);
            acc[hh*2+1] = fmaf(wh, xv.y, acc[hh*2+1]);
        }
    }
    bf16* yp = Y + (size_t)node*YW + lane*2;
    #pragma unroll
    for (int hh=0; hh<8; ++hh){
        bf16 b0 = __float2bfloat16(acc[hh*2]);
        bf16 b1 = __float2bfloat16(acc[hh*2+1]);
        ushort2 pk;
        pk.x = *(unsigned short*)&b0;
        pk.y = *(unsigned short*)&b1;
        *reinterpret_cast<ushort2*>(yp + hh*KIN) = pk;
    }
}

// ================= final GEMM: out = Y @ WcT^T + b_eff + b_lin ===
__global__ __launch_bounds__(256) void k_gemm64(
    const bf16* __restrict__ A, const bf16* __restrict__ BT,
    const float* __restrict__ b_eff, const float* __restrict__ b_lin,
    float* __restrict__ C)
{
    __shared__ __align__(16) char smem_raw[24576];
    bf16* sA = (bf16*)smem_raw;
    bf16* sB = (bf16*)(smem_raw + 8192);
    const int tid = threadIdx.x;
    int m0 = blockIdx.x * 64;
    int n0 = blockIdx.y * 128;
    Acc24 acc;
    gemm64x128(A + (size_t)m0*YW, YW, BT + (size_t)n0*YW, YW, YW, sA, sB, tid, acc);
    const int lane = tid & 63;
    const int w = tid >> 6, wm = w >> 1, wn = w & 1;
    const int m16 = lane & 15, q = lane >> 4;
    #pragma unroll
    for (int i=0;i<2;++i){
        int row_base = m0 + wm*32 + i*16 + q*4;
        #pragma unroll
        for (int j=0;j<4;++j){
            int col = n0 + wn*64 + j*16 + m16;
            float bval = b_eff[col] + b_lin[col];
            #pragma unroll
            for (int r=0;r<4;++r)
                C[(size_t)(row_base + r)*NOUT + col] = acc.a[i][j][r] + bval;
        }
    }
}

extern "C" void kernel_launch(void* const* d_in, const int* in_sizes, int n_in,
                              void* d_out, int out_size, void* d_ws, size_t ws_size,
                              hipStream_t stream)
{
    const float* x       = (const float*)d_in[0];
    const int*   eidx    = (const int*)  d_in[1];
    const float* W_gat   = (const float*)d_in[2];
    const float* b_gat   = (const float*)d_in[3];
    const float* att_src = (const float*)d_in[4];
    const float* att_dst = (const float*)d_in[5];
    const float* W_lin   = (const float*)d_in[6];
    const float* b_lin   = (const float*)d_in[7];
    float* out = (float*)d_out;

    char* p = (char*)d_ws;
    auto alloc = [&](size_t bytes){ void* r = (void*)p; p += (bytes + 255) & ~(size_t)255; return r; };
    bf16*  Wg     = (bf16*) alloc((size_t)KIN*HC*2);      // 1 MB
    bf16*  WcT    = (bf16*) alloc((size_t)NOUT*YW*2);     // 1 MB
    bf16*  Ybuf   = (bf16*) alloc((size_t)NN*YW*2);       // 16.4 MB
    float* v      = (float*)alloc((size_t)KIN*16*4);
    float* a_src  = (float*)alloc((size_t)NN*NH*4);
    float* a_dst  = (float*)alloc((size_t)NN*NH*4);
    int*   esrc   = (int*)  alloc((size_t)NN*MAXDEG*4);   // 2 MB
    // zero-init group (contiguous)
    int*   cursors= (int*)  alloc((size_t)NN*4);
    float* b_eff  = (float*)alloc((size_t)NOUT*4);
    if ((size_t)(p - (char*)d_ws) > ws_size) return;

    hipMemsetAsync(cursors, 0, (size_t)NN*4 + NOUT*4, stream);  // cursors + b_eff
    k_phaseA<<<PHA_NB, 256, 0, stream>>>(b_gat, W_gat, att_src, att_dst, W_lin,
                                         eidx, Wg, v, b_eff, cursors, esrc);
    k_phaseB<<<PHB_NB, 256, 0, stream>>>(Wg, W_lin, WcT, x, v, a_src, a_dst);
    k_agg<<<NN/4, 256, 0, stream>>>(cursors, esrc, a_src, a_dst, x, Ybuf);
    k_gemm64<<<dim3(NN/64, NOUT/128), 256, 0, stream>>>(Ybuf, WcT, b_eff, b_lin, out);
}